// Round 2
// baseline (1038.749 us; speedup 1.0000x reference)
//
#include <hip/hip_runtime.h>
#include <math.h>

#define N_ 100
#define G_ 100
#define E_ 128

typedef _Float16 half4 __attribute__((ext_vector_type(4)));
typedef _Float16 half8 __attribute__((ext_vector_type(8)));
typedef float f32x4 __attribute__((ext_vector_type(4)));

#define MFMA32(a,b,c) __builtin_amdgcn_mfma_f32_16x16x32_f16(a,b,c,0,0,0)
#define MFMA16(a,b,c) __builtin_amdgcn_mfma_f32_16x16x16f16(a,b,c,0,0,0)

// ---- prep: fp16 hi/lo split transposed weights into ws ----
// ws layout (fp16 elements): mat m in {0:Wsum(=Wqf+Wql),1:Wk,2:Wv,3:Wc}:
//   hi plane @ m*32768, lo plane @ m*32768+16384, each [o=128][i=128] (W^T)
extern "C" __global__ void prep_weights(const float* __restrict__ Wqf,
                                        const float* __restrict__ Wql,
                                        const float* __restrict__ Wk,
                                        const float* __restrict__ Wv,
                                        const float* __restrict__ Wc,
                                        _Float16* __restrict__ ws) {
    int t = blockIdx.x * 256 + threadIdx.x;      // 0..65535
    int m = t >> 14, r = t & 16383;
    int o = r & 127, i = r >> 7;
    float v;
    if      (m == 0) v = Wqf[i * 128 + o] + Wql[i * 128 + o];
    else if (m == 1) v = Wk [i * 128 + o];
    else if (m == 2) v = Wv [i * 128 + o];
    else             v = Wc [i * 128 + o];
    _Float16 h = (_Float16)v;
    _Float16 l = (_Float16)(v - (float)h);
    ws[m * 32768 + o * 128 + i]         = h;     // W^T[o][i] hi
    ws[m * 32768 + 16384 + o * 128 + i] = l;     // lo
}

// LDS element offsets (fp16 elements). total 40576 el = 81152 B  (<= 81920 for 2 blocks/CU)
#define OFF_NH 0                    // nodes hi [112][136] (rows 100..111 zero)
#define OFF_NL 15232                // nodes lo
#define OFF_KH 30464                // K hi [112][24] (cols d=0..15, one head; rows 100..111 zero)
#define OFF_KL 33152                // K lo
#define OFF_VH 35840                // V^T hi [16][124] (row e_local, col n; n>=100 zero)
#define OFF_VL 37824                // V^T lo
#define OFF_SF 39808                // fp32: GRAPH[128]@0, QG[128]@128, BC[128]@256

extern "C" __global__ void __launch_bounds__(448, 4)
pomo_decoder(const float* __restrict__ nodes,   // [B,N,E]
             const float* __restrict__ last,    // [B,G,E]
             const float* __restrict__ mask,    // [B,G,N]
             const float* __restrict__ Wqg,     // [E,128] fp32
             const _Float16* __restrict__ ws,   // fp16 hi/lo transposed weights
             const float* __restrict__ bc,      // [128]
             float* __restrict__ out)           // [B,G,N]
{
    __shared__ _Float16 SB[40576];
    float* SF = (float*)(SB + OFF_SF);

    const int tid  = threadIdx.x;
    const int w    = tid >> 6;          // 0..6, wave w owns rows g = 16w..16w+15
    const int lane = tid & 63;
    const int lrow = lane & 15;
    const int lq   = lane >> 4;
    const int b    = blockIdx.x;

    const float* nb = nodes + (size_t)b * N_ * E_;
    const float* lb = last  + (size_t)b * G_ * E_;
    const float* mb = mask  + (size_t)b * G_ * N_;
    float*       ob = out   + (size_t)b * G_ * N_;

    const _Float16* WsH = ws;
    const _Float16* WsL = ws + 16384;
    const _Float16* WkH = ws + 32768;
    const _Float16* WkL = ws + 49152;
    const _Float16* WvH = ws + 65536;
    const _Float16* WvL = ws + 81920;
    const _Float16* WcH = ws + 98304;
    const _Float16* WcL = ws + 114688;

    // ---------- phase 0: stage nodes (fp16 hi/lo) with fused column-sum partials ----------
    {
        const int c32 = tid & 31;            // float4 column group (col = c32*4)
        const int r0  = tid >> 5;            // 0..13
        const float4* nb4 = (const float4*)nb;
        float sx = 0.f, sy = 0.f, sz = 0.f, sw = 0.f;
        #pragma unroll
        for (int k = 0; k < 8; ++k) {
            const int r = r0 + 14 * k;
            if (r < 100) {
                float4 v = nb4[r * 32 + c32];
                half4 h, l;
                h[0]=(_Float16)v.x; l[0]=(_Float16)(v.x-(float)h[0]);
                h[1]=(_Float16)v.y; l[1]=(_Float16)(v.y-(float)h[1]);
                h[2]=(_Float16)v.z; l[2]=(_Float16)(v.z-(float)h[2]);
                h[3]=(_Float16)v.w; l[3]=(_Float16)(v.w-(float)h[3]);
                *(half4*)&SB[OFF_NH + r*136 + c32*4] = h;
                *(half4*)&SB[OFF_NL + r*136 + c32*4] = l;
                sx += v.x; sy += v.y; sz += v.z; sw += v.w;
            }
        }
        float4 cs; cs.x = sx; cs.y = sy; cs.z = sz; cs.w = sw;
        ((float4*)(SB + OFF_KH))[r0 * 32 + c32] = cs;   // partials [14][32] float4
        // zero nodes pad rows 100..111
        for (int t2 = tid; t2 < 1632; t2 += 448) {
            SB[OFF_NH + 13600 + t2] = (_Float16)0.f;
            SB[OFF_NL + 13600 + t2] = (_Float16)0.f;
        }
        if (tid < 128) SF[256 + tid] = bc[tid];
    }
    __syncthreads();

    // graph mean: reduce 14 partials per column
    if (tid < 128) {
        const float* SFP = (const float*)(SB + OFF_KH);
        float s = 0.f;
        #pragma unroll
        for (int j = 0; j < 14; ++j) s += SFP[j * 128 + tid];
        SF[tid] = s * 0.01f;
    }
    __syncthreads();

    // qg = graph @ Wqg : 3-way split over e (e == c mod 3), 4 chains each
    if (tid < 384) {
        const int o = tid & 127, c = tid >> 7;
        float a0 = 0.f, a1 = 0.f, a2 = 0.f, a3 = 0.f;
        for (int e = c; e < 128; e += 12) {
            a0 = fmaf(SF[e], Wqg[e * 128 + o], a0);
            if (e + 3 < 128) a1 = fmaf(SF[e + 3], Wqg[(e + 3) * 128 + o], a1);
            if (e + 6 < 128) a2 = fmaf(SF[e + 6], Wqg[(e + 6) * 128 + o], a2);
            if (e + 9 < 128) a3 = fmaf(SF[e + 9], Wqg[(e + 9) * 128 + o], a3);
        }
        ((float*)(SB + OFF_KH))[2048 + c * 128 + o] = (a0 + a1) + (a2 + a3);
    } else {
        // idle threads zero K pad rows 100..111 (stay zero forever)
        for (int t2 = tid - 384; t2 < 288; t2 += 64) {
            SB[OFF_KH + 2400 + t2] = (_Float16)0.f;
            SB[OFF_KL + 2400 + t2] = (_Float16)0.f;
        }
    }
    __syncthreads();
    if (tid < 128) {
        const float* Q = (const float*)(SB + OFF_KH) + 2048;
        SF[128 + tid] = Q[tid] + Q[128 + tid] + Q[256 + tid];
    }
    __syncthreads();

    // ---------- P1: q^T[e][g] = (Wsum^T . last^T) + qg, kept in registers ----------
    // lane holds q[g = 16w + lrow][e = 16et + 4lq + r]  (hi/lo half4 per et)
    half4 qh[8], qlo[8];
    {
        const int grow = (w * 16 + lrow > 99) ? 99 : (w * 16 + lrow);
        const float* lrp = lb + (size_t)grow * 128;
        f32x4 acc[8];
        #pragma unroll
        for (int et = 0; et < 8; ++et) { f32x4 z = {0.f,0.f,0.f,0.f}; acc[et] = z; }
        #pragma unroll
        for (int kk = 0; kk < 4; ++kk) {
            float4 f0 = *(const float4*)(lrp + kk * 32 + lq * 8);
            float4 f1 = *(const float4*)(lrp + kk * 32 + lq * 8 + 4);
            half8 bh, bl;
            bh[0]=(_Float16)f0.x; bl[0]=(_Float16)(f0.x-(float)bh[0]);
            bh[1]=(_Float16)f0.y; bl[1]=(_Float16)(f0.y-(float)bh[1]);
            bh[2]=(_Float16)f0.z; bl[2]=(_Float16)(f0.z-(float)bh[2]);
            bh[3]=(_Float16)f0.w; bl[3]=(_Float16)(f0.w-(float)bh[3]);
            bh[4]=(_Float16)f1.x; bl[4]=(_Float16)(f1.x-(float)bh[4]);
            bh[5]=(_Float16)f1.y; bl[5]=(_Float16)(f1.y-(float)bh[5]);
            bh[6]=(_Float16)f1.z; bl[6]=(_Float16)(f1.z-(float)bh[6]);
            bh[7]=(_Float16)f1.w; bl[7]=(_Float16)(f1.w-(float)bh[7]);
            #pragma unroll
            for (int et = 0; et < 8; ++et) {
                const int wo = (et * 16 + lrow) * 128 + kk * 32 + lq * 8;
                half8 ah = *(const half8*)(WsH + wo);
                half8 al = *(const half8*)(WsL + wo);
                acc[et] = MFMA32(ah, bh, acc[et]);
                acc[et] = MFMA32(ah, bl, acc[et]);
                acc[et] = MFMA32(al, bh, acc[et]);
            }
        }
        #pragma unroll
        for (int et = 0; et < 8; ++et)
            #pragma unroll
            for (int r = 0; r < 4; ++r) {
                float qv = acc[et][r] + SF[128 + et * 16 + lq * 4 + r];
                qh[et][r]  = (_Float16)qv;
                qlo[et][r] = (_Float16)(qv - (float)qh[et][r]);
            }
    }

    const int gmrow = (w * 16 + lrow > 99) ? 99 : (w * 16 + lrow);

    // ---------- attention: 8 per-head phases ----------
    half4 oh[8], olo[8];   // O[g][16*h + 4lq + r] hi/lo
    #pragma unroll
    for (int h = 0; h < 8; ++h) {
        // ---- P2: project K[n][d] and V^T[e][n] for head h (14 tiles over 7 waves) ----
        #pragma unroll
        for (int i = 0; i < 2; ++i) {
            const int tt = w * 2 + i;           // 0..13
            const bool isK = (tt < 7);
            const int nt = isK ? tt : tt - 7;
            f32x4 a1 = {0.f,0.f,0.f,0.f}, a2 = a1, a3 = a1;
            if (isK) {
                #pragma unroll
                for (int kk = 0; kk < 4; ++kk) {
                    half8 ah = *(const half8*)&SB[OFF_NH + (nt*16 + lrow)*136 + kk*32 + lq*8];
                    half8 al = *(const half8*)&SB[OFF_NL + (nt*16 + lrow)*136 + kk*32 + lq*8];
                    const int wo = (h*16 + lrow)*128 + kk*32 + lq*8;
                    half8 bh = *(const half8*)(WkH + wo);
                    half8 bl = *(const half8*)(WkL + wo);
                    a1 = MFMA32(ah, bh, a1);
                    a2 = MFMA32(ah, bl, a2);
                    a3 = MFMA32(al, bh, a3);
                }
                #pragma unroll
                for (int r = 0; r < 4; ++r) {
                    const int n = nt*16 + lq*4 + r;
                    if (n < N_) {
                        float v = (a1[r] + a2[r]) + a3[r];
                        _Float16 hv = (_Float16)v;
                        SB[OFF_KH + n*24 + lrow] = hv;
                        SB[OFF_KL + n*24 + lrow] = (_Float16)(v - (float)hv);
                    }
                }
            } else {
                #pragma unroll
                for (int kk = 0; kk < 4; ++kk) {
                    const int wo = (h*16 + lrow)*128 + kk*32 + lq*8;
                    half8 ah = *(const half8*)(WvH + wo);
                    half8 al = *(const half8*)(WvL + wo);
                    half8 bh = *(const half8*)&SB[OFF_NH + (nt*16 + lrow)*136 + kk*32 + lq*8];
                    half8 bl = *(const half8*)&SB[OFF_NL + (nt*16 + lrow)*136 + kk*32 + lq*8];
                    a1 = MFMA32(ah, bh, a1);
                    a2 = MFMA32(ah, bl, a2);
                    a3 = MFMA32(al, bh, a3);
                }
                #pragma unroll
                for (int r = 0; r < 4; ++r) {
                    const int e = lq*4 + r;             // e_local 0..15
                    const int n = nt*16 + lrow;         // 0..111
                    float v = (n < N_) ? ((a1[r] + a2[r]) + a3[r]) : 0.f;
                    _Float16 hv = (_Float16)v;
                    SB[OFF_VH + e*124 + n] = hv;
                    SB[OFF_VL + e*124 + n] = (_Float16)(v - (float)hv);
                }
            }
        }
        __syncthreads();

        // ---- P3: S^T = K.q, softmax over n, O^T = V^T.P ----
        {
            f32x4 sc[7];
            #pragma unroll
            for (int nt = 0; nt < 7; ++nt) {
                half4 kh = *(const half4*)&SB[OFF_KH + (nt*16 + lrow)*24 + lq*4];
                half4 kl = *(const half4*)&SB[OFF_KL + (nt*16 + lrow)*24 + lq*4];
                f32x4 z = {0.f,0.f,0.f,0.f};
                z = MFMA16(kh, qh[h], z);
                z = MFMA16(kh, qlo[h], z);
                z = MFMA16(kl, qh[h], z);
                sc[nt] = z;   // S^T[n = 16nt+4lq+r][g = 16w+lrow]
            }
            float mx = -INFINITY;
            #pragma unroll
            for (int nt = 0; nt < 7; ++nt) {
                float4 m = {0.f, 0.f, 0.f, 0.f};
                if (nt < 6 || lq == 0)
                    m = *(const float4*)(mb + (size_t)gmrow * 100 + nt*16 + lq*4);
                const float* mp = (const float*)&m;
                #pragma unroll
                for (int r = 0; r < 4; ++r) {
                    const int n = nt*16 + lq*4 + r;
                    float s = (n < N_) ? sc[nt][r] * 0.25f + mp[r] : -INFINITY;
                    sc[nt][r] = s;
                    mx = fmaxf(mx, s);
                }
            }
            mx = fmaxf(mx, __shfl_xor(mx, 16));
            mx = fmaxf(mx, __shfl_xor(mx, 32));
            float sum = 0.f;
            half4 ph[7], pl[7];
            #pragma unroll
            for (int nt = 0; nt < 7; ++nt)
                #pragma unroll
                for (int r = 0; r < 4; ++r) {
                    float p = __expf(sc[nt][r] - mx);
                    sum += p;
                    ph[nt][r] = (_Float16)p;
                    pl[nt][r] = (_Float16)(p - (float)ph[nt][r]);
                }
            sum += __shfl_xor(sum, 16);
            sum += __shfl_xor(sum, 32);
            const float inv = 1.f / sum;
            f32x4 o1 = {0.f,0.f,0.f,0.f}, o2 = o1, o3 = o1;
            #pragma unroll
            for (int nt = 0; nt < 7; ++nt) {
                half4 vh = *(const half4*)&SB[OFF_VH + lrow*124 + nt*16 + lq*4];
                half4 vl = *(const half4*)&SB[OFF_VL + lrow*124 + nt*16 + lq*4];
                o1 = MFMA16(vh, ph[nt], o1);
                o2 = MFMA16(vh, pl[nt], o2);
                o3 = MFMA16(vl, ph[nt], o3);
            }
            #pragma unroll
            for (int r = 0; r < 4; ++r) {
                float v = ((o1[r] + o2[r]) + o3[r]) * inv;   // O[g][16h+4lq+r]
                oh[h][r]  = (_Float16)v;
                olo[h][r] = (_Float16)(v - (float)oh[h][r]);
            }
        }
        if (h < 7) __syncthreads();
    }

    // ---------- P4: mh^T[e][g] = Wc^T . O^T + bc, kept in registers ----------
    half4 mhh[8], mhl[8];
    #pragma unroll
    for (int et = 0; et < 8; ++et) {
        f32x4 a1 = {0.f,0.f,0.f,0.f}, a2 = a1, a3 = a1;
        #pragma unroll
        for (int kc = 0; kc < 8; ++kc) {
            const int wo = (et*16 + lrow)*128 + kc*16 + lq*4;
            half4 ah = *(const half4*)(WcH + wo);
            half4 al = *(const half4*)(WcL + wo);
            a1 = MFMA16(ah, oh[kc], a1);
            a2 = MFMA16(ah, olo[kc], a2);
            a3 = MFMA16(al, oh[kc], a3);
        }
        #pragma unroll
        for (int r = 0; r < 4; ++r) {
            float v = ((a1[r] + a2[r]) + a3[r]) + SF[256 + et*16 + lq*4 + r];
            mhh[et][r] = (_Float16)v;
            mhl[et][r] = (_Float16)(v - (float)mhh[et][r]);
        }
    }

    // ---------- P5: S2^T[n][g] = nodes . mh^T, tanh clip, softmax, direct store ----------
    {
        f32x4 s2[7];
        #pragma unroll
        for (int nt = 0; nt < 7; ++nt) {
            f32x4 a1 = {0.f,0.f,0.f,0.f}, a2 = a1, a3 = a1;
            #pragma unroll
            for (int kc = 0; kc < 8; ++kc) {
                half4 ah = *(const half4*)&SB[OFF_NH + (nt*16 + lrow)*136 + kc*16 + lq*4];
                half4 al = *(const half4*)&SB[OFF_NL + (nt*16 + lrow)*136 + kc*16 + lq*4];
                a1 = MFMA16(ah, mhh[kc], a1);
                a2 = MFMA16(ah, mhl[kc], a2);
                a3 = MFMA16(al, mhh[kc], a3);
            }
            s2[nt] = (a1 + a2) + a3;
        }
        float mx = -INFINITY;
        #pragma unroll
        for (int nt = 0; nt < 7; ++nt) {
            float4 m = {0.f, 0.f, 0.f, 0.f};
            if (nt < 6 || lq == 0)
                m = *(const float4*)(mb + (size_t)gmrow * 100 + nt*16 + lq*4);
            const float* mp = (const float*)&m;
            #pragma unroll
            for (int r = 0; r < 4; ++r) {
                const int n = nt*16 + lq*4 + r;
                float s;
                if (n < N_) {
                    float x = s2[nt][r] * 0.08838834764831845f;   // 1/sqrt(128)
                    x = fminf(fmaxf(x, -15.f), 15.f);
                    const float e2 = __expf(2.f * x);
                    const float th = 1.f - 2.f / (e2 + 1.f);
                    s = 10.f * th + mp[r];
                } else s = -INFINITY;
                s2[nt][r] = s;
                mx = fmaxf(mx, s);
            }
        }
        mx = fmaxf(mx, __shfl_xor(mx, 16));
        mx = fmaxf(mx, __shfl_xor(mx, 32));
        float sum = 0.f;
        #pragma unroll
        for (int nt = 0; nt < 7; ++nt)
            #pragma unroll
            for (int r = 0; r < 4; ++r) {
                float p = __expf(s2[nt][r] - mx);
                s2[nt][r] = p;
                sum += p;
            }
        sum += __shfl_xor(sum, 16);
        sum += __shfl_xor(sum, 32);
        const float inv = 1.f / sum;
        const int g = w * 16 + lrow;
        if (g < G_) {
            #pragma unroll
            for (int nt = 0; nt < 7; ++nt) {
                float4 t;
                t.x = s2[nt][0] * inv; t.y = s2[nt][1] * inv;
                t.z = s2[nt][2] * inv; t.w = s2[nt][3] * inv;
                if (nt < 6)           *(float4*)&ob[(size_t)g * 100 + nt*16 + lq*4] = t;
                else if (lq == 0)     *(float4*)&ob[(size_t)g * 100 + 96] = t;
            }
        }
    }
}

extern "C" void kernel_launch(void* const* d_in, const int* in_sizes, int n_in,
                              void* d_out, int out_size, void* d_ws, size_t ws_size,
                              hipStream_t stream) {
    const float* nodes = (const float*)d_in[0];
    const float* last  = (const float*)d_in[1];
    const float* mask  = (const float*)d_in[2];
    const float* Wqg   = (const float*)d_in[3];
    const float* Wqf   = (const float*)d_in[4];
    const float* Wql   = (const float*)d_in[5];
    const float* Wk    = (const float*)d_in[6];
    const float* Wv    = (const float*)d_in[7];
    const float* Wc    = (const float*)d_in[8];
    const float* bc    = (const float*)d_in[9];
    float* out = (float*)d_out;
    _Float16* ws = (_Float16*)d_ws;              // needs 262144 B

    hipLaunchKernelGGL(prep_weights, dim3(256), dim3(256), 0, stream,
                       Wqf, Wql, Wk, Wv, Wc, ws);

    const int B = in_sizes[0] / (N_ * E_);       // 2048
    hipLaunchKernelGGL(pomo_decoder, dim3(B), dim3(448), 0, stream,
                       nodes, last, mask, Wqg, ws, bc, out);
}

// Round 3
// 825.149 us; speedup vs baseline: 1.2589x; 1.2589x over previous
//
#include <hip/hip_runtime.h>
#include <math.h>

#define N_ 100
#define G_ 100
#define E_ 128

typedef _Float16 half4 __attribute__((ext_vector_type(4)));
typedef _Float16 half8 __attribute__((ext_vector_type(8)));
typedef float f32x4 __attribute__((ext_vector_type(4)));

#define MFMA32(a,b,c) __builtin_amdgcn_mfma_f32_16x16x32_f16(a,b,c,0,0,0)
#define MFMA16(a,b,c) __builtin_amdgcn_mfma_f32_16x16x16f16(a,b,c,0,0,0)

// ---- prep: fp16 hi/lo split transposed weights into ws ----
// ws layout (fp16 elements): mat m in {0:Wsum(=Wqf+Wql),1:Wk,2:Wv,3:Wc}:
//   hi plane @ m*32768, lo plane @ m*32768+16384, each [o=128][i=128] (W^T)
extern "C" __global__ void prep_weights(const float* __restrict__ Wqf,
                                        const float* __restrict__ Wql,
                                        const float* __restrict__ Wk,
                                        const float* __restrict__ Wv,
                                        const float* __restrict__ Wc,
                                        _Float16* __restrict__ ws) {
    int t = blockIdx.x * 256 + threadIdx.x;      // 0..65535
    int m = t >> 14, r = t & 16383;
    int o = r & 127, i = r >> 7;
    float v;
    if      (m == 0) v = Wqf[i * 128 + o] + Wql[i * 128 + o];
    else if (m == 1) v = Wk [i * 128 + o];
    else if (m == 2) v = Wv [i * 128 + o];
    else             v = Wc [i * 128 + o];
    _Float16 h = (_Float16)v;
    _Float16 l = (_Float16)(v - (float)h);
    ws[m * 32768 + o * 128 + i]         = h;     // W^T[o][i] hi
    ws[m * 32768 + 16384 + o * 128 + i] = l;     // lo
}

// LDS element offsets (fp16 elements). total 40576 el = 81152 B (2 blocks/CU by LDS)
#define OFF_NH 0                    // nodes hi [112][136] (rows 100..111 zero)
#define OFF_NL 15232                // nodes lo
#define OFF_KH 30464                // K double-buffer [2][112][24] (d cols, one head)
#define OFF_VH 35840                // V^T double-buffer [2][16][124] (row e, col n)
#define OFF_SF 39808                // fp32: GRAPH[128]@0, QG[128]@128, BC[128]@256

extern "C" __global__ void __launch_bounds__(448, 4)
pomo_decoder(const float* __restrict__ nodes,   // [B,N,E]
             const float* __restrict__ last,    // [B,G,E]
             const float* __restrict__ mask,    // [B,G,N]
             const float* __restrict__ Wqg,     // [E,128] fp32
             const _Float16* __restrict__ ws,   // fp16 hi/lo transposed weights
             const float* __restrict__ bc,      // [128]
             float* __restrict__ out)           // [B,G,N]
{
    __shared__ _Float16 SB[40576];
    float* SF = (float*)(SB + OFF_SF);

    const int tid  = threadIdx.x;
    const int w    = tid >> 6;          // 0..6, wave w owns rows g = 16w..16w+15
    const int lane = tid & 63;
    const int lrow = lane & 15;
    const int lq   = lane >> 4;
    const int b    = blockIdx.x;

    const float* nb = nodes + (size_t)b * N_ * E_;
    const float* lb = last  + (size_t)b * G_ * E_;
    const float* mb = mask  + (size_t)b * G_ * N_;
    float*       ob = out   + (size_t)b * G_ * N_;

    const _Float16* WsH = ws;
    const _Float16* WsL = ws + 16384;
    const _Float16* WkH = ws + 32768;
    const _Float16* WvH = ws + 65536;
    const _Float16* WcH = ws + 98304;
    const _Float16* WcL = ws + 114688;

    // ---------- phase 0: stage nodes (fp16 hi/lo) with fused column-sum partials ----------
    {
        const int c32 = tid & 31;            // float4 column group (col = c32*4)
        const int r0  = tid >> 5;            // 0..13
        const float4* nb4 = (const float4*)nb;
        float sx = 0.f, sy = 0.f, sz = 0.f, sw = 0.f;
        #pragma unroll
        for (int k = 0; k < 8; ++k) {
            const int r = r0 + 14 * k;
            if (r < 100) {
                float4 v = nb4[r * 32 + c32];
                half4 h, l;
                h[0]=(_Float16)v.x; l[0]=(_Float16)(v.x-(float)h[0]);
                h[1]=(_Float16)v.y; l[1]=(_Float16)(v.y-(float)h[1]);
                h[2]=(_Float16)v.z; l[2]=(_Float16)(v.z-(float)h[2]);
                h[3]=(_Float16)v.w; l[3]=(_Float16)(v.w-(float)h[3]);
                *(half4*)&SB[OFF_NH + r*136 + c32*4] = h;
                *(half4*)&SB[OFF_NL + r*136 + c32*4] = l;
                sx += v.x; sy += v.y; sz += v.z; sw += v.w;
            }
        }
        float4 cs; cs.x = sx; cs.y = sy; cs.z = sz; cs.w = sw;
        ((float4*)(SB + OFF_KH))[r0 * 32 + c32] = cs;   // partials [14][32] float4
        // zero nodes pad rows 100..111
        for (int t2 = tid; t2 < 1632; t2 += 448) {
            SB[OFF_NH + 13600 + t2] = (_Float16)0.f;
            SB[OFF_NL + 13600 + t2] = (_Float16)0.f;
        }
        if (tid < 128) SF[256 + tid] = bc[tid];
    }
    __syncthreads();

    // graph mean: reduce 14 partials per column
    if (tid < 128) {
        const float* SFP = (const float*)(SB + OFF_KH);
        float s = 0.f;
        #pragma unroll
        for (int j = 0; j < 14; ++j) s += SFP[j * 128 + tid];
        SF[tid] = s * 0.01f;
    }
    __syncthreads();

    // qg = graph @ Wqg : 3-way split over e, 4 chains each (scratch in KH region)
    if (tid < 384) {
        const int o = tid & 127, c = tid >> 7;
        float a0 = 0.f, a1 = 0.f, a2 = 0.f, a3 = 0.f;
        for (int e = c; e < 128; e += 12) {
            a0 = fmaf(SF[e], Wqg[e * 128 + o], a0);
            if (e + 3 < 128) a1 = fmaf(SF[e + 3], Wqg[(e + 3) * 128 + o], a1);
            if (e + 6 < 128) a2 = fmaf(SF[e + 6], Wqg[(e + 6) * 128 + o], a2);
            if (e + 9 < 128) a3 = fmaf(SF[e + 9], Wqg[(e + 9) * 128 + o], a3);
        }
        ((float*)(SB + OFF_KH))[2048 + c * 128 + o] = (a0 + a1) + (a2 + a3);
    }
    __syncthreads();
    if (tid < 128) {
        const float* Q = (const float*)(SB + OFF_KH) + 2048;
        SF[128 + tid] = Q[tid] + Q[128 + tid] + Q[256 + tid];
    }
    __syncthreads();

    const int gmrow = (w * 16 + lrow > 99) ? 99 : (w * 16 + lrow);

    // ---------- P1: q^T[e][g] = (Wsum^T . last^T) + qg -> fp16 single, registers ----------
    // lane holds q[g = 16w + lrow][e = 16et + 4lq + r]  (half4 per et)
    half4 qh[8];
    {
        const float* lrp = lb + (size_t)gmrow * 128;
        f32x4 acc[8];
        #pragma unroll
        for (int et = 0; et < 8; ++et) { f32x4 z = {0.f,0.f,0.f,0.f}; acc[et] = z; }
        #pragma unroll
        for (int kk = 0; kk < 4; ++kk) {
            float4 f0 = *(const float4*)(lrp + kk * 32 + lq * 8);
            float4 f1 = *(const float4*)(lrp + kk * 32 + lq * 8 + 4);
            half8 bh;
            bh[0]=(_Float16)f0.x; bh[1]=(_Float16)f0.y;
            bh[2]=(_Float16)f0.z; bh[3]=(_Float16)f0.w;
            bh[4]=(_Float16)f1.x; bh[5]=(_Float16)f1.y;
            bh[6]=(_Float16)f1.z; bh[7]=(_Float16)f1.w;
            #pragma unroll
            for (int et = 0; et < 8; ++et) {
                const int wo = (et * 16 + lrow) * 128 + kk * 32 + lq * 8;
                half8 ah = *(const half8*)(WsH + wo);
                half8 al = *(const half8*)(WsL + wo);
                acc[et] = MFMA32(ah, bh, acc[et]);
                acc[et] = MFMA32(al, bh, acc[et]);
            }
        }
        #pragma unroll
        for (int et = 0; et < 8; ++et)
            #pragma unroll
            for (int r = 0; r < 4; ++r)
                qh[et][r] = (_Float16)(acc[et][r] + SF[128 + et * 16 + lq * 4 + r]);
    }

    // ---------- attention: 8 per-head phases, K/V double-buffered, 1 barrier/phase ----------
    f32x4 mh_acc[8];
    #pragma unroll
    for (int et = 0; et < 8; ++et) { f32x4 z = {0.f,0.f,0.f,0.f}; mh_acc[et] = z; }

    // prologue: project head 0 into buffer 0
    #pragma unroll
    for (int i = 0; i < 2; ++i) {
        const int tt = w * 2 + i;
        const bool isK = (tt < 7);
        const int nt = isK ? tt : tt - 7;
        f32x4 a1 = {0.f,0.f,0.f,0.f};
        if (isK) {
            #pragma unroll
            for (int kk = 0; kk < 4; ++kk) {
                half8 ah = *(const half8*)&SB[OFF_NH + (nt*16 + lrow)*136 + kk*32 + lq*8];
                half8 bh = *(const half8*)(WkH + (0*16 + lrow)*128 + kk*32 + lq*8);
                a1 = MFMA32(ah, bh, a1);
            }
            #pragma unroll
            for (int r = 0; r < 4; ++r) {
                const int n = nt*16 + lq*4 + r;
                if (n < N_) SB[OFF_KH + n*24 + lrow] = (_Float16)a1[r];
            }
        } else {
            #pragma unroll
            for (int kk = 0; kk < 4; ++kk) {
                half8 ah = *(const half8*)(WvH + (0*16 + lrow)*128 + kk*32 + lq*8);
                half8 bh = *(const half8*)&SB[OFF_NH + (nt*16 + lrow)*136 + kk*32 + lq*8];
                a1 = MFMA32(ah, bh, a1);
            }
            #pragma unroll
            for (int r = 0; r < 4; ++r) {
                const int e = lq*4 + r;
                const int n = nt*16 + lrow;
                SB[OFF_VH + e*124 + n] = (n < N_) ? (_Float16)a1[r] : (_Float16)0.f;
            }
        }
    }
    __syncthreads();

    #pragma unroll
    for (int h = 0; h < 8; ++h) {
        const int cur = h & 1;
        const int koff = OFF_KH + cur * 2688;
        const int voff = OFF_VH + cur * 1984;

        // ---- project head h+1 into the other buffer (overlaps with P3 below) ----
        if (h < 7) {
            const int nkoff = OFF_KH + (cur ^ 1) * 2688;
            const int nvoff = OFF_VH + (cur ^ 1) * 1984;
            #pragma unroll
            for (int i = 0; i < 2; ++i) {
                const int tt = w * 2 + i;
                const bool isK = (tt < 7);
                const int nt = isK ? tt : tt - 7;
                f32x4 a1 = {0.f,0.f,0.f,0.f};
                if (isK) {
                    #pragma unroll
                    for (int kk = 0; kk < 4; ++kk) {
                        half8 ah = *(const half8*)&SB[OFF_NH + (nt*16 + lrow)*136 + kk*32 + lq*8];
                        half8 bh = *(const half8*)(WkH + ((h+1)*16 + lrow)*128 + kk*32 + lq*8);
                        a1 = MFMA32(ah, bh, a1);
                    }
                    #pragma unroll
                    for (int r = 0; r < 4; ++r) {
                        const int n = nt*16 + lq*4 + r;
                        if (n < N_) SB[nkoff + n*24 + lrow] = (_Float16)a1[r];
                    }
                } else {
                    #pragma unroll
                    for (int kk = 0; kk < 4; ++kk) {
                        half8 ah = *(const half8*)(WvH + ((h+1)*16 + lrow)*128 + kk*32 + lq*8);
                        half8 bh = *(const half8*)&SB[OFF_NH + (nt*16 + lrow)*136 + kk*32 + lq*8];
                        a1 = MFMA32(ah, bh, a1);
                    }
                    #pragma unroll
                    for (int r = 0; r < 4; ++r) {
                        const int e = lq*4 + r;
                        const int n = nt*16 + lrow;
                        SB[nvoff + e*124 + n] = (n < N_) ? (_Float16)a1[r] : (_Float16)0.f;
                    }
                }
            }
        }

        // ---- P3: S^T = K.q (single), softmax, O = V.P, accumulate mh ----
        {
            f32x4 sc[7];
            #pragma unroll
            for (int nt = 0; nt < 7; ++nt) {
                half4 kh = *(const half4*)&SB[koff + (nt*16 + lrow)*24 + lq*4];
                f32x4 z = {0.f,0.f,0.f,0.f};
                sc[nt] = MFMA16(kh, qh[h], z);   // S^T[n=16nt+4lq+r][g=16w+lrow]
            }
            float mx = -INFINITY;
            #pragma unroll
            for (int nt = 0; nt < 7; ++nt) {
                float4 m = {0.f, 0.f, 0.f, 0.f};
                if (nt < 6 || lq == 0)
                    m = *(const float4*)(mb + (size_t)gmrow * 100 + nt*16 + lq*4);
                const float* mp = (const float*)&m;
                #pragma unroll
                for (int r = 0; r < 4; ++r) {
                    const int n = nt*16 + lq*4 + r;
                    float s = (n < N_) ? sc[nt][r] * 0.25f + mp[r] : -INFINITY;
                    sc[nt][r] = s;
                    mx = fmaxf(mx, s);
                }
            }
            mx = fmaxf(mx, __shfl_xor(mx, 16));
            mx = fmaxf(mx, __shfl_xor(mx, 32));
            float sum = 0.f;
            half4 ph[7];
            #pragma unroll
            for (int nt = 0; nt < 7; ++nt)
                #pragma unroll
                for (int r = 0; r < 4; ++r) {
                    float p = __expf(sc[nt][r] - mx);
                    sum += p;
                    ph[nt][r] = (_Float16)p;
                }
            sum += __shfl_xor(sum, 16);
            sum += __shfl_xor(sum, 32);
            const float inv = 1.f / sum;
            f32x4 o1 = {0.f,0.f,0.f,0.f};
            #pragma unroll
            for (int nt = 0; nt < 7; ++nt) {
                half4 vh = *(const half4*)&SB[voff + lrow*124 + nt*16 + lq*4];
                o1 = MFMA16(vh, ph[nt], o1);
            }
            half4 oht, olt;
            #pragma unroll
            for (int r = 0; r < 4; ++r) {
                float v = o1[r] * inv;           // O[g][16h+4lq+r]
                oht[r] = (_Float16)v;
                olt[r] = (_Float16)(v - (float)oht[r]);
            }
            // mh_acc[et] += Wc^T[et-rows][h-slice] . O_h  (split Wc and O)
            #pragma unroll
            for (int et = 0; et < 8; ++et) {
                const int wo = (et*16 + lrow)*128 + h*16 + lq*4;
                half4 ah = *(const half4*)(WcH + wo);
                half4 al = *(const half4*)(WcL + wo);
                mh_acc[et] = MFMA16(ah, oht, mh_acc[et]);
                mh_acc[et] = MFMA16(ah, olt, mh_acc[et]);
                mh_acc[et] = MFMA16(al, oht, mh_acc[et]);
            }
        }
        if (h < 7) __syncthreads();
    }

    // ---------- P4 epilogue: mh = mh_acc + bc -> hi/lo fp16 ----------
    half4 mhh[8], mhl[8];
    #pragma unroll
    for (int et = 0; et < 8; ++et)
        #pragma unroll
        for (int r = 0; r < 4; ++r) {
            float v = mh_acc[et][r] + SF[256 + et*16 + lq*4 + r];
            mhh[et][r] = (_Float16)v;
            mhl[et][r] = (_Float16)(v - (float)mhh[et][r]);
        }

    // ---------- P5: S2^T[n][g] = nodes . mh^T (full split), tanh clip, softmax, store ----------
    {
        f32x4 s2[7];
        #pragma unroll
        for (int nt = 0; nt < 7; ++nt) {
            f32x4 a1 = {0.f,0.f,0.f,0.f}, a2 = a1, a3 = a1;
            #pragma unroll
            for (int kc = 0; kc < 8; ++kc) {
                half4 ah = *(const half4*)&SB[OFF_NH + (nt*16 + lrow)*136 + kc*16 + lq*4];
                half4 al = *(const half4*)&SB[OFF_NL + (nt*16 + lrow)*136 + kc*16 + lq*4];
                a1 = MFMA16(ah, mhh[kc], a1);
                a2 = MFMA16(ah, mhl[kc], a2);
                a3 = MFMA16(al, mhh[kc], a3);
            }
            s2[nt] = (a1 + a2) + a3;
        }
        float mx = -INFINITY;
        #pragma unroll
        for (int nt = 0; nt < 7; ++nt) {
            float4 m = {0.f, 0.f, 0.f, 0.f};
            if (nt < 6 || lq == 0)
                m = *(const float4*)(mb + (size_t)gmrow * 100 + nt*16 + lq*4);
            const float* mp = (const float*)&m;
            #pragma unroll
            for (int r = 0; r < 4; ++r) {
                const int n = nt*16 + lq*4 + r;
                float s;
                if (n < N_) {
                    float x = s2[nt][r] * 0.08838834764831845f;   // 1/sqrt(128)
                    x = fminf(fmaxf(x, -15.f), 15.f);
                    const float e2 = __expf(2.f * x);
                    const float th = 1.f - 2.f / (e2 + 1.f);
                    s = 10.f * th + mp[r];
                } else s = -INFINITY;
                s2[nt][r] = s;
                mx = fmaxf(mx, s);
            }
        }
        mx = fmaxf(mx, __shfl_xor(mx, 16));
        mx = fmaxf(mx, __shfl_xor(mx, 32));
        float sum = 0.f;
        #pragma unroll
        for (int nt = 0; nt < 7; ++nt)
            #pragma unroll
            for (int r = 0; r < 4; ++r) {
                float p = __expf(s2[nt][r] - mx);
                s2[nt][r] = p;
                sum += p;
            }
        sum += __shfl_xor(sum, 16);
        sum += __shfl_xor(sum, 32);
        const float inv = 1.f / sum;
        const int g = w * 16 + lrow;
        if (g < G_) {
            #pragma unroll
            for (int nt = 0; nt < 7; ++nt) {
                float4 t;
                t.x = s2[nt][0] * inv; t.y = s2[nt][1] * inv;
                t.z = s2[nt][2] * inv; t.w = s2[nt][3] * inv;
                if (nt < 6)           *(float4*)&ob[(size_t)g * 100 + nt*16 + lq*4] = t;
                else if (lq == 0)     *(float4*)&ob[(size_t)g * 100 + 96] = t;
            }
        }
    }
}

extern "C" void kernel_launch(void* const* d_in, const int* in_sizes, int n_in,
                              void* d_out, int out_size, void* d_ws, size_t ws_size,
                              hipStream_t stream) {
    const float* nodes = (const float*)d_in[0];
    const float* last  = (const float*)d_in[1];
    const float* mask  = (const float*)d_in[2];
    const float* Wqg   = (const float*)d_in[3];
    const float* Wqf   = (const float*)d_in[4];
    const float* Wql   = (const float*)d_in[5];
    const float* Wk    = (const float*)d_in[6];
    const float* Wv    = (const float*)d_in[7];
    const float* Wc    = (const float*)d_in[8];
    const float* bc    = (const float*)d_in[9];
    float* out = (float*)d_out;
    _Float16* ws = (_Float16*)d_ws;              // needs 262144 B

    hipLaunchKernelGGL(prep_weights, dim3(256), dim3(256), 0, stream,
                       Wqf, Wql, Wk, Wv, Wc, ws);

    const int B = in_sizes[0] / (N_ * E_);       // 2048
    hipLaunchKernelGGL(pomo_decoder, dim3(B), dim3(448), 0, stream,
                       nodes, last, mask, Wqg, ws, bc, out);
}